// Round 12
// baseline (24.375 us; speedup 1.0000x reference)
//
#include <hip/hip_runtime.h>
#include <math.h>

#define N_WAY 64
#define N_SUP 16
#define DIM   1024
#define N_QUERIES 4096
#define ROWS_PER_WAY 80
#define QT 16
#define NWORK 256         // worker blocks; +1 finalizer
#define NLEAF 32          // leaves per tree, 8 workers each
#define CTR_STRIDE 32     // u32 stride = 128B = one cacheline per counter
#define PROTO_ROOT (32 * CTR_STRIDE)
#define GEMM_LEAF0 33     // counter index of first gemm leaf
#define GEMM_ROOT  (65 * CTR_STRIDE)
#define CTR_BYTES  (66 * 128)

typedef __attribute__((ext_vector_type(8))) short short8;
typedef __attribute__((ext_vector_type(4))) float f32x4;

// bf16 round-to-nearest-even
__device__ __forceinline__ unsigned short bf16_rne(float f) {
  unsigned u = __float_as_uint(f);
  return (unsigned short)((u + 0x7fffu + ((u >> 16) & 1u)) >> 16);
}

// Packed B-fragment layout (validated round 3): short8 index (kb*4+tile)*64+lane,
// lane = kgrp*16 + n15 holds way tile*16+n15, k = kb*32 + kgrp*8 + j.

// ---------------------------------------------------------------------------
// Single fused kernel, grid = 257 x 512.
// Block 0: finalizer — relax-polls gemm root; reduces 512 partials; stores out.
// Blocks 1..256 (blk=bid-1): worker —
//   1) issue 16-query A loads (HBM latency hides under proto)
//   2) proto quarter (way=blk>>2, cg=blk&3): publish packed bf16 phi as
//      relaxed agent u64 stores + pnorm partial; wave-0 vmcnt(0); tree arrive
//   3) relax-poll proto root (s_sleep backoff); ONE acquire (L1/L2 inv)
//   4) plain B loads (fresh post-inv), 16 MFMAs, K-reduce, fused softmax
//   5) publish (loss,correct) partials via gemm tree (R9/R10/R11 mechanism)
// Counters are zeroed by a preceding 8.4KB memset node (d_ws is poisoned).
// ---------------------------------------------------------------------------
__global__ __launch_bounds__(512) void fused_kernel(
    const float* __restrict__ x, unsigned short* __restrict__ phi,
    float* __restrict__ pnorm4, float* __restrict__ part,
    unsigned* __restrict__ ctrs, float* __restrict__ out) {
  const int tid  = threadIdx.x;
  const int lane = tid & 63;

  if (blockIdx.x == 0) {
    // ---------------- finalizer block (R11-validated) ----------------
    if (tid < 64) {
      if (lane == 0) {
        while (__hip_atomic_load(&ctrs[GEMM_ROOT], __ATOMIC_RELAXED,
                                 __HIP_MEMORY_SCOPE_AGENT) < NLEAF)
          __builtin_amdgcn_s_sleep(2);
      }
      float l = 0.f, c = 0.f;
      #pragma unroll
      for (int r = 0; r < 4; ++r) {
        int i = lane + 64 * r;
        l += __hip_atomic_load(&part[2 * i],     __ATOMIC_RELAXED,
                               __HIP_MEMORY_SCOPE_AGENT);
        c += __hip_atomic_load(&part[2 * i + 1], __ATOMIC_RELAXED,
                               __HIP_MEMORY_SCOPE_AGENT);
      }
      #pragma unroll
      for (int off = 32; off > 0; off >>= 1) {
        l += __shfl_down(l, off);
        c += __shfl_down(c, off);
      }
      if (lane == 0) {
        out[0] = l * (1.0f / (float)N_QUERIES);
        out[1] = c * (100.0f / (float)N_QUERIES);
      }
    }
    return;
  }

  // ---------------- worker blocks ----------------
  __shared__ float Sp[8][16][68];   // per-wave partial tiles (padded)
  __shared__ float So[16][68];      // reduced logits
  __shared__ float pnL[64];
  float4* pars = (float4*)&Sp[0][0][0];  // aliased: proto staging, pre-MFMA only

  const int blk  = blockIdx.x - 1;  // 0..255
  const int wv   = tid >> 6;
  const int lrow = lane & 15;
  const int kgrp = lane >> 4;
  const int qb   = blk * QT;

  // ---- 1) issue A loads early ----
  const int qrow = (qb >> 6) * ROWS_PER_WAY + N_SUP + (qb & 63) + lrow;
  const float* arow = x + (size_t)qrow * DIM + kgrp * 8;
  f32x4 a0[4], a1[4];
  #pragma unroll
  for (int s = 0; s < 4; ++s) {
    a0[s] = *(const f32x4*)(arow + (wv * 4 + s) * 32);
    a1[s] = *(const f32x4*)(arow + (wv * 4 + s) * 32 + 4);
  }

  // ---- 2) proto quarter: way = blk>>2, columns quarter cg = blk&3 ----
  const int way = blk >> 2;
  const int cg  = blk & 3;
  if (tid < 256) {
    const int lc = tid & 63;            // local f32x4 col
    const int sg = tid >> 6;            // support group (4 rows)
    const float4* x4 = (const float4*)x;
    const int base = way * ROWS_PER_WAY * (DIM / 4);
    const int col = cg * 64 + lc;
    float4 a = make_float4(0.f, 0.f, 0.f, 0.f);
    #pragma unroll
    for (int r = 0; r < 4; ++r) {
      float4 v = x4[base + (sg * 4 + r) * (DIM / 4) + col];
      a.x += v.x; a.y += v.y; a.z += v.z; a.w += v.w;
    }
    pars[sg * 64 + lc] = a;
  }
  __syncthreads();
  if (tid < 64) {
    float4 p0 = pars[tid], p1 = pars[64 + tid], p2 = pars[128 + tid], p3 = pars[192 + tid];
    const float inv = 1.0f / 16.0f;
    float vals[4] = {(p0.x + p1.x + p2.x + p3.x) * inv,
                     (p0.y + p1.y + p2.y + p3.y) * inv,
                     (p0.z + p1.z + p2.z + p3.z) * inv,
                     (p0.w + p1.w + p2.w + p3.w) * inv};
    const int c   = cg * 64 + tid;      // f32x4 col 0..255
    const int kb2 = c >> 3, kg2 = (c >> 1) & 3, j0 = (c & 1) * 4;
    const int tile = way >> 4;
    const int ln = kg2 * 16 + (way & 15);
    const int uidx = ((kb2 * 4 + tile) * 64 + ln) * 8 + j0;
    unsigned long long pv =
        (unsigned long long)bf16_rne(vals[0]) |
        ((unsigned long long)bf16_rne(vals[1]) << 16) |
        ((unsigned long long)bf16_rne(vals[2]) << 32) |
        ((unsigned long long)bf16_rne(vals[3]) << 48);
    __hip_atomic_store((unsigned long long*)(phi + uidx), pv,
                       __ATOMIC_RELAXED, __HIP_MEMORY_SCOPE_AGENT);
    float pq = vals[0] * vals[0] + vals[1] * vals[1] +
               vals[2] * vals[2] + vals[3] * vals[3];
    #pragma unroll
    for (int off = 32; off > 0; off >>= 1) pq += __shfl_down(pq, off);
    if (tid == 0)
      __hip_atomic_store(&pnorm4[way * 4 + cg], pq,
                         __ATOMIC_RELAXED, __HIP_MEMORY_SCOPE_AGENT);
  }

  // ---- convert A to bf16 while publishes drain ----
  short8 ah[4];
  #pragma unroll
  for (int s = 0; s < 4; ++s)
    #pragma unroll
    for (int j = 0; j < 4; ++j) {
      ah[s][j]     = (short)bf16_rne(a0[s][j]);
      ah[s][4 + j] = (short)bf16_rne(a1[s][j]);
    }

  // ---- 3) tree arrival + poll + one acquire ----
  if (tid == 0) {
    asm volatile("s_waitcnt vmcnt(0)" ::: "memory");  // wave-0 publishes -> LLC
    unsigned leaf = (unsigned)(blk & (NLEAF - 1));
    unsigned ol = __hip_atomic_fetch_add(&ctrs[leaf * CTR_STRIDE], 1u,
                                         __ATOMIC_RELAXED,
                                         __HIP_MEMORY_SCOPE_AGENT);
    if (ol == (NWORK / NLEAF) - 1)
      __hip_atomic_fetch_add(&ctrs[PROTO_ROOT], 1u, __ATOMIC_RELAXED,
                             __HIP_MEMORY_SCOPE_AGENT);
    while (__hip_atomic_load(&ctrs[PROTO_ROOT], __ATOMIC_RELAXED,
                             __HIP_MEMORY_SCOPE_AGENT) < NLEAF)
      __builtin_amdgcn_s_sleep(8);
    // single acquire: invalidate L1/L2 so plain phi/pnorm loads are fresh
    (void)__hip_atomic_load(&ctrs[PROTO_ROOT], __ATOMIC_ACQUIRE,
                            __HIP_MEMORY_SCOPE_AGENT);
  }
  __syncthreads();

  // ---- 4) B loads (plain, post-acquire), pnL, 16 MFMAs ----
  const short8* bhp = (const short8*)phi + lane;
  short8 bhv[4][4];
  #pragma unroll
  for (int s = 0; s < 4; ++s)
    #pragma unroll
    for (int t = 0; t < 4; ++t)
      bhv[s][t] = bhp[((wv * 4 + s) * 4 + t) * 64];

  if (tid < 64)
    pnL[tid] = pnorm4[4 * tid] + pnorm4[4 * tid + 1] +
               pnorm4[4 * tid + 2] + pnorm4[4 * tid + 3];

  f32x4 acc[4];
  #pragma unroll
  for (int t = 0; t < 4; ++t) acc[t] = (f32x4){0.f, 0.f, 0.f, 0.f};
  #pragma unroll
  for (int s = 0; s < 4; ++s)
    #pragma unroll
    for (int t = 0; t < 4; ++t)
      acc[t] = __builtin_amdgcn_mfma_f32_16x16x32_bf16(ah[s], bhv[s][t], acc[t], 0, 0, 0);

  // per-wave partials: C/D layout col(way)=lane&15, row(q)=kgrp*4+r (validated)
  #pragma unroll
  for (int t = 0; t < 4; ++t)
    #pragma unroll
    for (int r = 0; r < 4; ++r)
      Sp[wv][kgrp * 4 + r][t * 16 + lrow] = acc[t][r];
  __syncthreads();

  // reduce 8 K-slices, apply 2*dot - pnorm
  for (int i = tid; i < QT * N_WAY; i += 512) {
    int q = i >> 6, w = i & 63;
    float s = 0.f;
    #pragma unroll
    for (int v = 0; v < 8; ++v) s += Sp[v][q][w];
    So[q][w] = 2.f * s - pnL[w];
  }
  __syncthreads();

  // ---- 5) fused log-softmax + argmax + publish ----
  if (tid < 64) {
    const int q = lane & 15;
    const int wq = lane >> 4;
    const int label = qb >> 6;
    float m = -INFINITY; int arg = 0;
    #pragma unroll
    for (int i = 0; i < 16; ++i) {
      int w = wq * 16 + i;
      float v = So[q][w];
      if (v > m) { m = v; arg = w; }
    }
    #pragma unroll
    for (int off = 16; off < 64; off <<= 1) {
      float om = __shfl_xor(m, off);
      int oa = __shfl_xor(arg, off);
      if (om > m || (om == m && oa < arg)) { m = om; arg = oa; }
    }
    float sum = 0.f;
    #pragma unroll
    for (int i = 0; i < 16; ++i) sum += expf(So[q][wq * 16 + i] - m);
    sum += __shfl_xor(sum, 16);
    sum += __shfl_xor(sum, 32);

    float lossq = 0.f, corr = 0.f;
    if (lane < 16) {
      lossq = m + logf(sum) - So[q][label];
      corr = (arg == label) ? 1.f : 0.f;
    }
    #pragma unroll
    for (int off = 8; off > 0; off >>= 1) {
      lossq += __shfl_down(lossq, off);
      corr  += __shfl_down(corr, off);
    }
    if (lane == 0) {
      __hip_atomic_store(&part[2 * blk],     lossq, __ATOMIC_RELAXED,
                         __HIP_MEMORY_SCOPE_AGENT);
      __hip_atomic_store(&part[2 * blk + 1], corr,  __ATOMIC_RELAXED,
                         __HIP_MEMORY_SCOPE_AGENT);
      asm volatile("s_waitcnt vmcnt(0)" ::: "memory");  // publishes reach LLC
      unsigned leaf = (unsigned)(blk & (NLEAF - 1));
      unsigned ol = __hip_atomic_fetch_add(&ctrs[(GEMM_LEAF0 + leaf) * CTR_STRIDE],
                                           1u, __ATOMIC_RELAXED,
                                           __HIP_MEMORY_SCOPE_AGENT);
      if (ol == (NWORK / NLEAF) - 1)
        __hip_atomic_fetch_add(&ctrs[GEMM_ROOT], 1u, __ATOMIC_RELAXED,
                               __HIP_MEMORY_SCOPE_AGENT);
    }
  }
}

extern "C" void kernel_launch(void* const* d_in, const int* in_sizes, int n_in,
                              void* d_out, int out_size, void* d_ws, size_t ws_size,
                              hipStream_t stream) {
  (void)in_sizes; (void)n_in; (void)out_size; (void)ws_size;
  const float* x = (const float*)d_in[0];
  float* out = (float*)d_out;

  unsigned short* phi = (unsigned short*)d_ws;        // 64*1024 u16 packed
  float* pnorm4 = (float*)(phi + N_WAY * DIM);        // 256 f32
  float* part   = pnorm4 + 256;                       // 512 f32
  unsigned* ctrs = (unsigned*)(part + 2 * NWORK);     // 66 x 128B-strided u32

  hipMemsetAsync(ctrs, 0, CTR_BYTES, stream);         // counters must start 0
  hipLaunchKernelGGL(fused_kernel, dim3(NWORK + 1), dim3(512), 0, stream,
                     x, phi, pnorm4, part, ctrs, out);
}

// Round 13
// 17.183 us; speedup vs baseline: 1.4186x; 1.4186x over previous
//
#include <hip/hip_runtime.h>
#include <math.h>

#define N_WAY 64
#define N_SUP 16
#define DIM   1024
#define N_QUERIES 4096
#define ROWS_PER_WAY 80
#define QT 16
#define GEMM_BLOCKS 256   // worker blocks (N_QUERIES / QT); +1 finalizer
#define NLEAF 32          // leaf counters, 8 workers each
#define CTR_STRIDE 32     // u32 stride = 128B = one cacheline per counter

typedef __attribute__((ext_vector_type(8))) short short8;
typedef __attribute__((ext_vector_type(4))) float f32x4;

// bf16 round-to-nearest-even
__device__ __forceinline__ unsigned short bf16_rne(float f) {
  unsigned u = __float_as_uint(f);
  return (unsigned short)((u + 0x7fffu + ((u >> 16) & 1u)) >> 16);
}

// Packed B-fragment layout (validated round 3): short8 index (kb*4+tile)*64+lane,
// lane = kgrp*16 + n15 holds way tile*16+n15, k = kb*32 + kgrp*8 + j.

// ---------------------------------------------------------------------------
// Kernel A: prototypes -> packed bf16 fragments + per-eighth pnorm partials.
// grid = 512 (8 blocks per way, 32 f32x4-cols each), block = 128 (2 waves;
// 2 blocks/CU for latency hiding). No atomics; plain stores published by the
// node boundary. Block 0 zeroes the gemm tree counters.
// ---------------------------------------------------------------------------
__global__ __launch_bounds__(128) void proto_kernel(
    const float* __restrict__ x, unsigned short* __restrict__ phi,
    float* __restrict__ pnorm8, unsigned* __restrict__ ctrs) {
  const int way = blockIdx.x >> 3;
  const int cg8 = blockIdx.x & 7;       // column eighth (32 f32x4 cols)
  const int t   = threadIdx.x;          // 0..127
  const int lc  = t & 31;               // local f32x4 col
  const int sg  = t >> 5;               // support group (4 rows each)
  const float4* x4 = (const float4*)x;
  const int base = way * ROWS_PER_WAY * (DIM / 4);
  const int col = cg8 * 32 + lc;        // f32x4 col 0..255

  if (blockIdx.x == 0 && t <= NLEAF) ctrs[t * CTR_STRIDE] = 0u;  // replay-safe

  float4 a = make_float4(0.f, 0.f, 0.f, 0.f);
  #pragma unroll
  for (int r = 0; r < 4; ++r) {
    float4 v = x4[base + (sg * 4 + r) * (DIM / 4) + col];
    a.x += v.x; a.y += v.y; a.z += v.z; a.w += v.w;
  }
  __shared__ float4 pars[4][32];
  pars[sg][lc] = a;
  __syncthreads();

  if (t < 32) {
    float4 a0 = pars[0][t], a1 = pars[1][t], a2 = pars[2][t], a3 = pars[3][t];
    const float inv = 1.0f / 16.0f;
    float vals[4] = {(a0.x + a1.x + a2.x + a3.x) * inv,
                     (a0.y + a1.y + a2.y + a3.y) * inv,
                     (a0.z + a1.z + a2.z + a3.z) * inv,
                     (a0.w + a1.w + a2.w + a3.w) * inv};
    const int c   = cg8 * 32 + t;       // f32x4 col 0..255
    const int kb2 = c >> 3, kg2 = (c >> 1) & 3, j0 = (c & 1) * 4;
    const int tile = way >> 4;
    const int ln = kg2 * 16 + (way & 15);
    const int uidx = ((kb2 * 4 + tile) * 64 + ln) * 8 + j0;
    *(ushort4*)(phi + uidx) = make_ushort4(bf16_rne(vals[0]), bf16_rne(vals[1]),
                                           bf16_rne(vals[2]), bf16_rne(vals[3]));

    float pq = vals[0] * vals[0] + vals[1] * vals[1] +
               vals[2] * vals[2] + vals[3] * vals[3];
    #pragma unroll
    for (int off = 16; off > 0; off >>= 1) pq += __shfl_down(pq, off);
    if (t == 0) pnorm8[way * 8 + cg8] = pq;   // plain store, no atomic
  }
}

// ---------------------------------------------------------------------------
// Kernel B (R11-validated): grid = 257. Block 0 = finalizer: relax-polls the
// tree root while workers compute; on root==NLEAF, relax-loads the 512
// partials (LLC is the coherence point) and plain-stores d_out. Blocks
// 1..256 = workers: bf16 MFMA gemm + fused softmax; publish partials
// (relaxed stores + vmcnt(0)); leaf fetch-add; leaf-last bumps root.
// ---------------------------------------------------------------------------
__global__ __launch_bounds__(512) void gemm_kernel(
    const float* __restrict__ x, const unsigned short* __restrict__ phi,
    const float* __restrict__ pnorm8, float* __restrict__ part,
    unsigned* __restrict__ ctrs, float* __restrict__ out) {
  const int tid  = threadIdx.x;
  const int lane = tid & 63;

  if (blockIdx.x == 0) {
    // ---------------- finalizer block ----------------
    if (tid < 64) {
      if (lane == 0) {
        while (__hip_atomic_load(&ctrs[NLEAF * CTR_STRIDE], __ATOMIC_RELAXED,
                                 __HIP_MEMORY_SCOPE_AGENT) < NLEAF)
          __builtin_amdgcn_s_sleep(1);
      }
      // reconverged: all 256 publishes are in LLC
      float l = 0.f, c = 0.f;
      #pragma unroll
      for (int r = 0; r < 4; ++r) {
        int i = lane + 64 * r;      // partial-pair index 0..255
        l += __hip_atomic_load(&part[2 * i],     __ATOMIC_RELAXED,
                               __HIP_MEMORY_SCOPE_AGENT);
        c += __hip_atomic_load(&part[2 * i + 1], __ATOMIC_RELAXED,
                               __HIP_MEMORY_SCOPE_AGENT);
      }
      #pragma unroll
      for (int off = 32; off > 0; off >>= 1) {
        l += __shfl_down(l, off);
        c += __shfl_down(c, off);
      }
      if (lane == 0) {
        out[0] = l * (1.0f / (float)N_QUERIES);
        out[1] = c * (100.0f / (float)N_QUERIES);
      }
    }
    return;
  }

  // ---------------- worker blocks ----------------
  __shared__ float Sp[8][16][68];   // per-wave partial tiles (padded)
  __shared__ float So[16][68];      // reduced logits
  __shared__ float pnL[64];

  const int blk  = blockIdx.x - 1;  // 0..255
  const int wv   = tid >> 6;
  const int lrow = lane & 15;
  const int kgrp = lane >> 4;
  const int qb   = blk * QT;

  // ---- A loads first (HBM-bound: start early), then B (LLC/L2-hot) ----
  const int qrow = (qb >> 6) * ROWS_PER_WAY + N_SUP + (qb & 63) + lrow;
  const float* arow = x + (size_t)qrow * DIM + kgrp * 8;
  f32x4 a0[4], a1[4];
  #pragma unroll
  for (int s = 0; s < 4; ++s) {
    a0[s] = *(const f32x4*)(arow + (wv * 4 + s) * 32);
    a1[s] = *(const f32x4*)(arow + (wv * 4 + s) * 32 + 4);
  }
  const short8* bhp = (const short8*)phi + lane;
  short8 bhv[4][4];
  #pragma unroll
  for (int s = 0; s < 4; ++s)
    #pragma unroll
    for (int t = 0; t < 4; ++t)
      bhv[s][t] = bhp[((wv * 4 + s) * 4 + t) * 64];

  if (tid < 64) {
    f32x4 p0 = *(const f32x4*)(pnorm8 + 8 * tid);
    f32x4 p1 = *(const f32x4*)(pnorm8 + 8 * tid + 4);
    pnL[tid] = (p0[0] + p0[1] + p0[2] + p0[3]) +
               (p1[0] + p1[1] + p1[2] + p1[3]);
  }

  // ---- convert A to bf16 (RNE) ----
  short8 ah[4];
  #pragma unroll
  for (int s = 0; s < 4; ++s)
    #pragma unroll
    for (int j = 0; j < 4; ++j) {
      ah[s][j]     = (short)bf16_rne(a0[s][j]);
      ah[s][4 + j] = (short)bf16_rne(a1[s][j]);
    }

  // ---- 16 MFMAs ----
  f32x4 acc[4];
  #pragma unroll
  for (int t = 0; t < 4; ++t) acc[t] = (f32x4){0.f, 0.f, 0.f, 0.f};
  #pragma unroll
  for (int s = 0; s < 4; ++s)
    #pragma unroll
    for (int t = 0; t < 4; ++t)
      acc[t] = __builtin_amdgcn_mfma_f32_16x16x32_bf16(ah[s], bhv[s][t], acc[t], 0, 0, 0);

  // per-wave partials: C/D layout col(way)=lane&15, row(q)=kgrp*4+r (validated)
  #pragma unroll
  for (int t = 0; t < 4; ++t)
    #pragma unroll
    for (int r = 0; r < 4; ++r)
      Sp[wv][kgrp * 4 + r][t * 16 + lrow] = acc[t][r];
  __syncthreads();

  // reduce 8 K-slices, apply 2*dot - pnorm
  for (int i = tid; i < QT * N_WAY; i += 512) {
    int q = i >> 6, w = i & 63;
    float s = 0.f;
    #pragma unroll
    for (int v = 0; v < 8; ++v) s += Sp[v][q][w];
    So[q][w] = 2.f * s - pnL[w];
  }
  __syncthreads();

  // fused log-softmax + argmax: wave 0, 64 lanes = 16 q x 4 way-quarters
  if (tid < 64) {
    const int q = lane & 15;
    const int wq = lane >> 4;
    const int label = qb >> 6;
    float m = -INFINITY; int arg = 0;
    #pragma unroll
    for (int i = 0; i < 16; ++i) {
      int w = wq * 16 + i;
      float v = So[q][w];
      if (v > m) { m = v; arg = w; }
    }
    #pragma unroll
    for (int off = 16; off < 64; off <<= 1) {
      float om = __shfl_xor(m, off);
      int oa = __shfl_xor(arg, off);
      if (om > m || (om == m && oa < arg)) { m = om; arg = oa; }
    }
    float sum = 0.f;
    #pragma unroll
    for (int i = 0; i < 16; ++i) sum += expf(So[q][wq * 16 + i] - m);
    sum += __shfl_xor(sum, 16);
    sum += __shfl_xor(sum, 32);

    float lossq = 0.f, corr = 0.f;
    if (lane < 16) {
      lossq = m + logf(sum) - So[q][label];
      corr = (arg == label) ? 1.f : 0.f;
    }
    #pragma unroll
    for (int off = 8; off > 0; off >>= 1) {
      lossq += __shfl_down(lossq, off);
      corr  += __shfl_down(corr, off);
    }

    // ---- publish + tree arrival (finalizer block is polling the root) ----
    if (lane == 0) {
      __hip_atomic_store(&part[2 * blk],     lossq, __ATOMIC_RELAXED,
                         __HIP_MEMORY_SCOPE_AGENT);
      __hip_atomic_store(&part[2 * blk + 1], corr,  __ATOMIC_RELAXED,
                         __HIP_MEMORY_SCOPE_AGENT);
      asm volatile("s_waitcnt vmcnt(0)" ::: "memory");  // publishes reach LLC
      unsigned leaf = (unsigned)(blk & (NLEAF - 1));
      unsigned ol = __hip_atomic_fetch_add(&ctrs[leaf * CTR_STRIDE], 1u,
                                           __ATOMIC_RELAXED,
                                           __HIP_MEMORY_SCOPE_AGENT);
      if (ol == (GEMM_BLOCKS / NLEAF) - 1)   // leaf-last (8th of this leaf)
        __hip_atomic_fetch_add(&ctrs[NLEAF * CTR_STRIDE], 1u,
                               __ATOMIC_RELAXED, __HIP_MEMORY_SCOPE_AGENT);
    }
  }
}

extern "C" void kernel_launch(void* const* d_in, const int* in_sizes, int n_in,
                              void* d_out, int out_size, void* d_ws, size_t ws_size,
                              hipStream_t stream) {
  (void)in_sizes; (void)n_in; (void)out_size; (void)ws_size;
  const float* x = (const float*)d_in[0];
  float* out = (float*)d_out;

  unsigned short* phi = (unsigned short*)d_ws;        // 64*1024 u16 packed
  float* pnorm8 = (float*)(phi + N_WAY * DIM);        // 512 f32
  float* part   = pnorm8 + 512;                       // 512 f32
  unsigned* ctrs = (unsigned*)(part + 2 * GEMM_BLOCKS); // 33 x 128B-strided u32

  hipLaunchKernelGGL(proto_kernel, dim3(512), dim3(128), 0, stream,
                     x, phi, pnorm8, ctrs);
  hipLaunchKernelGGL(gemm_kernel, dim3(GEMM_BLOCKS + 1), dim3(512), 0, stream,
                     x, phi, pnorm8, part, ctrs, out);
}

// Round 14
// 16.791 us; speedup vs baseline: 1.4517x; 1.0234x over previous
//
#include <hip/hip_runtime.h>
#include <math.h>

#define N_WAY 64
#define N_SUP 16
#define DIM   1024
#define N_QUERIES 4096
#define ROWS_PER_WAY 80
#define QT 16
#define GEMM_BLOCKS 256   // worker blocks (N_QUERIES / QT); +1 finalizer
#define NLEAF 32          // leaf counters, 8 workers each
#define CTR_STRIDE 32     // u32 stride = 128B = one cacheline per counter

typedef __attribute__((ext_vector_type(8))) short short8;
typedef __attribute__((ext_vector_type(4))) float f32x4;

// bf16 round-to-nearest-even
__device__ __forceinline__ unsigned short bf16_rne(float f) {
  unsigned u = __float_as_uint(f);
  return (unsigned short)((u + 0x7fffu + ((u >> 16) & 1u)) >> 16);
}

// Packed B-fragment layout (validated round 3): short8 index (kb*4+tile)*64+lane,
// lane = kgrp*16 + n15 holds way tile*16+n15, k = kb*32 + kgrp*8 + j.

// ---------------------------------------------------------------------------
// Kernel A: prototypes -> packed bf16 fragments + per-quarter pnorm partials.
// grid = 256 (4 blocks per way), block = 256. No atomics. Zeroes the 33
// tree counters (plain stores; node-boundary release publishes them).
// ---------------------------------------------------------------------------
__global__ __launch_bounds__(256) void proto_kernel(
    const float* __restrict__ x, unsigned short* __restrict__ phi,
    float* __restrict__ pnorm4, unsigned* __restrict__ ctrs) {
  const int way = blockIdx.x >> 2;
  const int cg  = blockIdx.x & 3;       // column quarter
  const int t   = threadIdx.x;
  const int lc  = t & 63;               // local f32x4 col
  const int sg  = t >> 6;               // support group (4 rows)
  const float4* x4 = (const float4*)x;
  const int base = way * ROWS_PER_WAY * (DIM / 4);
  const int col = cg * 64 + lc;         // f32x4 col 0..255

  if (blockIdx.x == 0 && t <= NLEAF) ctrs[t * CTR_STRIDE] = 0u;  // replay-safe

  float4 a = make_float4(0.f, 0.f, 0.f, 0.f);
  #pragma unroll
  for (int r = 0; r < 4; ++r) {
    float4 v = x4[base + (sg * 4 + r) * (DIM / 4) + col];
    a.x += v.x; a.y += v.y; a.z += v.z; a.w += v.w;
  }
  __shared__ float4 pars[4][64];
  pars[sg][lc] = a;
  __syncthreads();

  if (t < 64) {
    float4 a0 = pars[0][t], a1 = pars[1][t], a2 = pars[2][t], a3 = pars[3][t];
    const float inv = 1.0f / 16.0f;
    float vals[4] = {(a0.x + a1.x + a2.x + a3.x) * inv,
                     (a0.y + a1.y + a2.y + a3.y) * inv,
                     (a0.z + a1.z + a2.z + a3.z) * inv,
                     (a0.w + a1.w + a2.w + a3.w) * inv};
    const int c   = cg * 64 + t;        // f32x4 col 0..255
    const int kb2 = c >> 3, kg2 = (c >> 1) & 3, j0 = (c & 1) * 4;
    const int tile = way >> 4;
    const int ln = kg2 * 16 + (way & 15);
    const int uidx = ((kb2 * 4 + tile) * 64 + ln) * 8 + j0;
    *(ushort4*)(phi + uidx) = make_ushort4(bf16_rne(vals[0]), bf16_rne(vals[1]),
                                           bf16_rne(vals[2]), bf16_rne(vals[3]));

    float pq = vals[0] * vals[0] + vals[1] * vals[1] +
               vals[2] * vals[2] + vals[3] * vals[3];
    #pragma unroll
    for (int off = 32; off > 0; off >>= 1) pq += __shfl_down(pq, off);
    if (t == 0) pnorm4[way * 4 + cg] = pq;   // plain store, no atomic
  }
}

// ---------------------------------------------------------------------------
// Kernel B (R11-validated best): grid = 257. Block 0 = finalizer: relax-polls
// the tree root while workers compute; on root==NLEAF, relax-loads the 512
// partials (LLC is the coherence point) and plain-stores d_out. Blocks
// 1..256 = workers: bf16 MFMA gemm + fused softmax; publish partials
// (relaxed stores + vmcnt(0)); leaf fetch-add; leaf-last bumps root.
// ---------------------------------------------------------------------------
__global__ __launch_bounds__(512) void gemm_kernel(
    const float* __restrict__ x, const unsigned short* __restrict__ phi,
    const float* __restrict__ pnorm4, float* __restrict__ part,
    unsigned* __restrict__ ctrs, float* __restrict__ out) {
  const int tid  = threadIdx.x;
  const int lane = tid & 63;

  if (blockIdx.x == 0) {
    // ---------------- finalizer block ----------------
    if (tid < 64) {
      if (lane == 0) {
        while (__hip_atomic_load(&ctrs[NLEAF * CTR_STRIDE], __ATOMIC_RELAXED,
                                 __HIP_MEMORY_SCOPE_AGENT) < NLEAF)
          __builtin_amdgcn_s_sleep(2);
      }
      // reconverged: all 256 publishes are in LLC
      float l = 0.f, c = 0.f;
      #pragma unroll
      for (int r = 0; r < 4; ++r) {
        int i = lane + 64 * r;      // partial-pair index 0..255
        l += __hip_atomic_load(&part[2 * i],     __ATOMIC_RELAXED,
                               __HIP_MEMORY_SCOPE_AGENT);
        c += __hip_atomic_load(&part[2 * i + 1], __ATOMIC_RELAXED,
                               __HIP_MEMORY_SCOPE_AGENT);
      }
      #pragma unroll
      for (int off = 32; off > 0; off >>= 1) {
        l += __shfl_down(l, off);
        c += __shfl_down(c, off);
      }
      if (lane == 0) {
        out[0] = l * (1.0f / (float)N_QUERIES);
        out[1] = c * (100.0f / (float)N_QUERIES);
      }
    }
    return;
  }

  // ---------------- worker blocks ----------------
  __shared__ float Sp[8][16][68];   // per-wave partial tiles (padded)
  __shared__ float So[16][68];      // reduced logits
  __shared__ float pnL[64];

  const int blk  = blockIdx.x - 1;  // 0..255
  const int wv   = tid >> 6;
  const int lrow = lane & 15;
  const int kgrp = lane >> 4;
  const int qb   = blk * QT;

  // ---- A loads first (HBM-bound: start early), then B (LLC/L2-hot) ----
  const int qrow = (qb >> 6) * ROWS_PER_WAY + N_SUP + (qb & 63) + lrow;
  const float* arow = x + (size_t)qrow * DIM + kgrp * 8;
  f32x4 a0[4], a1[4];
  #pragma unroll
  for (int s = 0; s < 4; ++s) {
    a0[s] = *(const f32x4*)(arow + (wv * 4 + s) * 32);
    a1[s] = *(const f32x4*)(arow + (wv * 4 + s) * 32 + 4);
  }
  const short8* bhp = (const short8*)phi + lane;
  short8 bhv[4][4];
  #pragma unroll
  for (int s = 0; s < 4; ++s)
    #pragma unroll
    for (int t = 0; t < 4; ++t)
      bhv[s][t] = bhp[((wv * 4 + s) * 4 + t) * 64];

  if (tid < 64)
    pnL[tid] = pnorm4[4 * tid] + pnorm4[4 * tid + 1] +
               pnorm4[4 * tid + 2] + pnorm4[4 * tid + 3];

  // ---- convert A to bf16 (RNE) ----
  short8 ah[4];
  #pragma unroll
  for (int s = 0; s < 4; ++s)
    #pragma unroll
    for (int j = 0; j < 4; ++j) {
      ah[s][j]     = (short)bf16_rne(a0[s][j]);
      ah[s][4 + j] = (short)bf16_rne(a1[s][j]);
    }

  // ---- 16 MFMAs ----
  f32x4 acc[4];
  #pragma unroll
  for (int t = 0; t < 4; ++t) acc[t] = (f32x4){0.f, 0.f, 0.f, 0.f};
  #pragma unroll
  for (int s = 0; s < 4; ++s)
    #pragma unroll
    for (int t = 0; t < 4; ++t)
      acc[t] = __builtin_amdgcn_mfma_f32_16x16x32_bf16(ah[s], bhv[s][t], acc[t], 0, 0, 0);

  // per-wave partials: C/D layout col(way)=lane&15, row(q)=kgrp*4+r (validated)
  #pragma unroll
  for (int t = 0; t < 4; ++t)
    #pragma unroll
    for (int r = 0; r < 4; ++r)
      Sp[wv][kgrp * 4 + r][t * 16 + lrow] = acc[t][r];
  __syncthreads();

  // reduce 8 K-slices, apply 2*dot - pnorm
  for (int i = tid; i < QT * N_WAY; i += 512) {
    int q = i >> 6, w = i & 63;
    float s = 0.f;
    #pragma unroll
    for (int v = 0; v < 8; ++v) s += Sp[v][q][w];
    So[q][w] = 2.f * s - pnL[w];
  }
  __syncthreads();

  // fused log-softmax + argmax: wave 0, 64 lanes = 16 q x 4 way-quarters
  if (tid < 64) {
    const int q = lane & 15;
    const int wq = lane >> 4;
    const int label = qb >> 6;
    float m = -INFINITY; int arg = 0;
    #pragma unroll
    for (int i = 0; i < 16; ++i) {
      int w = wq * 16 + i;
      float v = So[q][w];
      if (v > m) { m = v; arg = w; }
    }
    #pragma unroll
    for (int off = 16; off < 64; off <<= 1) {
      float om = __shfl_xor(m, off);
      int oa = __shfl_xor(arg, off);
      if (om > m || (om == m && oa < arg)) { m = om; arg = oa; }
    }
    float sum = 0.f;
    #pragma unroll
    for (int i = 0; i < 16; ++i) sum += expf(So[q][wq * 16 + i] - m);
    sum += __shfl_xor(sum, 16);
    sum += __shfl_xor(sum, 32);

    float lossq = 0.f, corr = 0.f;
    if (lane < 16) {
      lossq = m + logf(sum) - So[q][label];
      corr = (arg == label) ? 1.f : 0.f;
    }
    #pragma unroll
    for (int off = 8; off > 0; off >>= 1) {
      lossq += __shfl_down(lossq, off);
      corr  += __shfl_down(corr, off);
    }

    // ---- publish + tree arrival (finalizer block is polling the root) ----
    if (lane == 0) {
      __hip_atomic_store(&part[2 * blk],     lossq, __ATOMIC_RELAXED,
                         __HIP_MEMORY_SCOPE_AGENT);
      __hip_atomic_store(&part[2 * blk + 1], corr,  __ATOMIC_RELAXED,
                         __HIP_MEMORY_SCOPE_AGENT);
      asm volatile("s_waitcnt vmcnt(0)" ::: "memory");  // publishes reach LLC
      unsigned leaf = (unsigned)(blk & (NLEAF - 1));
      unsigned ol = __hip_atomic_fetch_add(&ctrs[leaf * CTR_STRIDE], 1u,
                                           __ATOMIC_RELAXED,
                                           __HIP_MEMORY_SCOPE_AGENT);
      if (ol == (GEMM_BLOCKS / NLEAF) - 1)   // leaf-last (8th of this leaf)
        __hip_atomic_fetch_add(&ctrs[NLEAF * CTR_STRIDE], 1u,
                               __ATOMIC_RELAXED, __HIP_MEMORY_SCOPE_AGENT);
    }
  }
}

extern "C" void kernel_launch(void* const* d_in, const int* in_sizes, int n_in,
                              void* d_out, int out_size, void* d_ws, size_t ws_size,
                              hipStream_t stream) {
  (void)in_sizes; (void)n_in; (void)out_size; (void)ws_size;
  const float* x = (const float*)d_in[0];
  float* out = (float*)d_out;

  unsigned short* phi = (unsigned short*)d_ws;        // 64*1024 u16 packed
  float* pnorm4 = (float*)(phi + N_WAY * DIM);        // 256 f32
  float* part   = pnorm4 + 256;                       // 512 f32
  unsigned* ctrs = (unsigned*)(part + 2 * GEMM_BLOCKS); // 33 x 128B-strided u32

  hipLaunchKernelGGL(proto_kernel, dim3(256), dim3(256), 0, stream,
                     x, phi, pnorm4, ctrs);
  hipLaunchKernelGGL(gemm_kernel, dim3(GEMM_BLOCKS + 1), dim3(512), 0, stream,
                     x, phi, pnorm4, part, ctrs, out);
}